// Round 9
// baseline (1232.854 us; speedup 1.0000x reference)
//
#include <hip/hip_runtime.h>

// ---------------------------------------------------------------------------
// LSTM: out[t] = h_t for t in [0,256);  final (c,h) appended.
//   T=256, B=128, D=1024, U=1024, 4U=4096
// Pipeline (ws ~338MB):
//   k_convert   : inputs f32 -> bf16
//   k_transpose : kernelx/kernelh f32 [1024][4096] -> W^T bf16 [4096][1024]
//   k_gemm_bf   : xz = inputs_bf @ kernelx (m97 structure, unchanged)
//   k_scan      : single launch, 256 steps, 256 blocks = 256 CUs, 1/CU;
//                 8 groups x 32 blocks (g = blk&7, XCD-local).
//                 R9: full-step xz(t+1) register prefetch (issued after stage
//                 loads; retired by the publish vmcnt(1) ~1800cy later);
//                 quarter waits vmcnt(9/7/5/3); zlds barrier is lgkmcnt-only
//                 (no vmcnt drain); release barrier replaced by all-wave poll.
// ---------------------------------------------------------------------------

typedef float  f32x4 __attribute__((ext_vector_type(4)));
typedef float  f32x2 __attribute__((ext_vector_type(2)));
typedef __bf16 bf16x8 __attribute__((ext_vector_type(8)));
typedef unsigned short us8 __attribute__((ext_vector_type(8)));
typedef unsigned short us4 __attribute__((ext_vector_type(4)));
typedef unsigned int   u32x4 __attribute__((ext_vector_type(4)));

#define TT 256
#define BB 128
#define DD 1024
#define UU 1024
#define NZ 4096

typedef __attribute__((address_space(3))) unsigned       lds_u32;
typedef const __attribute__((address_space(1))) unsigned glob_u32;

__device__ __forceinline__ unsigned short f2bf(float x) {
  union { float f; unsigned u; } v; v.f = x;
  unsigned r = v.u + 0x7fffu + ((v.u >> 16) & 1u);   // RNE
  return (unsigned short)(r >> 16);
}
__device__ __forceinline__ float bf2f(unsigned short b) {
  union { unsigned u; float f; } v; v.u = ((unsigned)b) << 16;
  return v.f;
}
__device__ __forceinline__ float sigm(float x) { return 1.f / (1.f + __expf(-x)); }
__device__ __forceinline__ float tanh_(float x) { return 1.f - 2.f / (__expf(2.f * x) + 1.f); }

// ---------------- f32 -> bf16 bulk convert (8 elems/thread)
__global__ __launch_bounds__(256) void k_convert(const float* __restrict__ in,
                                                 unsigned short* __restrict__ out,
                                                 int n8) {
  int i = blockIdx.x * 256 + threadIdx.x;
  if (i >= n8) return;
  const float4 a = *(const float4*)(in + (size_t)i * 8);
  const float4 b = *(const float4*)(in + (size_t)i * 8 + 4);
  us8 v;
  v[0] = f2bf(a.x); v[1] = f2bf(a.y); v[2] = f2bf(a.z); v[3] = f2bf(a.w);
  v[4] = f2bf(b.x); v[5] = f2bf(b.y); v[6] = f2bf(b.z); v[7] = f2bf(b.w);
  *(us8*)(out + (size_t)i * 8) = v;
}

// ---------------- transpose+convert: in f32 [1024][4096] -> out bf16 [4096][1024]
__global__ __launch_bounds__(256) void k_transpose(const float* __restrict__ in,
                                                   unsigned short* __restrict__ out) {
  __shared__ unsigned short tile[64][72];
  const int ni = blockIdx.x;
  const int ki = blockIdx.y;
  const int t = threadIdx.x;
  const int c = t & 63, r0 = t >> 6;
#pragma unroll
  for (int rr = 0; rr < 16; ++rr) {
    int r = r0 * 16 + rr;
    tile[r][c] = f2bf(in[(size_t)(ki * 64 + r) * NZ + ni * 64 + c]);
  }
  __syncthreads();
  const int kcol = t & 63, ng = t >> 6;
#pragma unroll
  for (int cc = 0; cc < 16; ++cc) {
    int n_off = ng * 16 + cc;
    out[(size_t)(ni * 64 + n_off) * DD + ki * 64 + kcol] = tile[kcol][n_off];
  }
}

// ---------------- xz = A_bf16[32768][1024] @ WxT^T, m97 structure (unchanged)
__global__ __launch_bounds__(256, 2) void k_gemm_bf(const unsigned short* __restrict__ A,
                                                    const unsigned short* __restrict__ Bt,
                                                    unsigned short* __restrict__ C) {
  __shared__ unsigned short Al[2][128 * 64];
  __shared__ unsigned short Bl[2][128 * 64];
  const int bx = blockIdx.x;
  const int wgid = (bx & 7) * 1024 + (bx >> 3);
  const int tm = wgid >> 5, tn = wgid & 31;
  const int tid = threadIdx.x;
  const int wave = tid >> 6, lane = tid & 63;
  const int wr = wave >> 1, wc = wave & 1;
  const int l15 = lane & 15, kg = lane >> 4;

  f32x4 acc[4][4] = {};   // [ni][mi]

  const int srow = tid >> 3;
  const int scol = (tid & 7) * 8;
  const unsigned sdst = tid * 8;

  auto stage = [&](int buf, int kt) {
#pragma unroll
    for (int i = 0; i < 4; ++i) {
      __builtin_amdgcn_global_load_lds(
          (glob_u32*)(A  + (size_t)(tm * 128 + i * 32 + srow) * DD + kt * 64 + scol),
          (lds_u32*)&Al[buf][i * 2048 + sdst], 16, 0, 0);
      __builtin_amdgcn_global_load_lds(
          (glob_u32*)(Bt + (size_t)(tn * 128 + i * 32 + srow) * DD + kt * 64 + scol),
          (lds_u32*)&Bl[buf][i * 2048 + sdst], 16, 0, 0);
    }
  };

  stage(0, 0);
  __syncthreads();

  for (int kt = 0; kt < 16; ++kt) {
    const int buf = kt & 1;
    if (kt < 15) stage(buf ^ 1, kt + 1);
#pragma unroll
    for (int ks = 0; ks < 2; ++ks) {
      bf16x8 af[4], bfr[4];
#pragma unroll
      for (int mi = 0; mi < 4; ++mi)
        af[mi] = *(const bf16x8*)&Al[buf][(wr * 64 + mi * 16 + l15) * 64 + ks * 32 + kg * 8];
#pragma unroll
      for (int ni = 0; ni < 4; ++ni)
        bfr[ni] = *(const bf16x8*)&Bl[buf][(wc * 64 + ni * 16 + l15) * 64 + ks * 32 + kg * 8];
#pragma unroll
      for (int mi = 0; mi < 4; ++mi)
#pragma unroll
        for (int ni = 0; ni < 4; ++ni)
          acc[ni][mi] = __builtin_amdgcn_mfma_f32_16x16x32_bf16(bfr[ni], af[mi], acc[ni][mi], 0, 0, 0);
    }
    __syncthreads();
  }

#pragma unroll
  for (int mi = 0; mi < 4; ++mi) {
    const size_t row = (size_t)tm * 128 + wr * 64 + mi * 16 + l15;
#pragma unroll
    for (int ni = 0; ni < 4; ++ni) {
      const size_t col = (size_t)tn * 128 + wc * 64 + ni * 16 + kg * 4;
      us4 v;
      v[0] = f2bf(acc[ni][mi][0]); v[1] = f2bf(acc[ni][mi][1]);
      v[2] = f2bf(acc[ni][mi][2]); v[3] = f2bf(acc[ni][mi][3]);
      *(us4*)(C + row * NZ + col) = v;
    }
  }
}

// ---------------- scan: quarter-pipelined staging, full-step xz prefetch
// VMEM FIFO per step: [out(t-1)?][st1..st8][xz(t+1) x4] -> quarter waits
// vmcnt(9/7/5/3) guarantee the quarter's 2 stage loads retired in both the
// out-present and out-drained cases; publish vmcnt(1) retires xz+h.
#define SCAN_QUARTER(Q, VMSTR)                                                  \
  {                                                                             \
    asm volatile("s_waitcnt " VMSTR ::: "memory");                              \
    __builtin_amdgcn_sched_barrier(0);                                          \
    *(u32x4*)(hlds_c + sbase + (Q) * 512)         = sv[(Q) * 2];                \
    *(u32x4*)(hlds_c + sbase + 16384 + (Q) * 512) = sv[(Q) * 2 + 1];            \
    asm volatile("s_waitcnt lgkmcnt(0)" ::: "memory");                          \
    __builtin_amdgcn_sched_barrier(0);                                          \
    __builtin_amdgcn_s_barrier();                                               \
    _Pragma("unroll")                                                           \
    for (int ks = (Q) * 8; ks < (Q) * 8 + 8; ++ks) {                            \
      const char* p = ((ks & 1) ? hp1 : hp0) + (ks >> 1) * 128;                 \
      bf16x8 a = *(const bf16x8*)p;                                             \
      acc0 = __builtin_amdgcn_mfma_f32_16x16x32_bf16(a, __builtin_bit_cast(bf16x8, w0[ks]), acc0, 0, 0, 0); \
      acc1 = __builtin_amdgcn_mfma_f32_16x16x32_bf16(a, __builtin_bit_cast(bf16x8, w1[ks]), acc1, 0, 0, 0); \
    }                                                                           \
  }

__global__ __launch_bounds__(256, 1) void k_scan(const float* __restrict__ init_cs,
                                                 const int* __restrict__ masks,
                                                 const unsigned short* __restrict__ WhT,
                                                 const float* __restrict__ bias,
                                                 const unsigned short* __restrict__ xz,
                                                 float* __restrict__ out,
                                                 unsigned short* __restrict__ hglob,
                                                 unsigned* __restrict__ flags) {
  __shared__ char  hlds_c[32768];               // 32KB h tile (swizzled layout)
  __shared__ float zlds[4][16][33];
  __shared__ int   mlds[TT * 16 + 16];          // masks [t][er], +pad

  const int tid = threadIdx.x;
  const int wave = tid >> 6, lane = tid & 63;
  const int l15 = lane & 15, kg = lane >> 4;
  const int blk = blockIdx.x;
  const int g = blk & 7;
  const int sb = blk >> 3;
  const int u0 = sb * 32;
  const int row0 = g * 16;
  unsigned* fl = flags + g * 64;                // 256B stride per group

  // ---- Wh fragments resident in registers, pinned
  u32x4 w0[32], w1[32];
  {
    const size_t r0 = (size_t)(wave * UU + u0 + l15) * DD;
    const size_t r1 = (size_t)(wave * UU + u0 + 16 + l15) * DD;
#pragma unroll
    for (int ks = 0; ks < 32; ++ks) {
      w0[ks] = *(const u32x4*)(WhT + r0 + ks * 32 + kg * 8);
      w1[ks] = *(const u32x4*)(WhT + r1 + ks * 32 + kg * 8);
    }
#pragma unroll
    for (int ks = 0; ks < 32; ++ks) {
      asm volatile("" : "+v"(w0[ks]));
      asm volatile("" : "+v"(w1[ks]));
    }
  }

  // ---- stage masks to LDS: mlds[t*16+er] = masks[t][row0+er]
  for (int i = 0; i < 16; ++i) {
    int idx = i * 256 + tid;
    mlds[idx] = masks[(size_t)(idx >> 4) * BB + row0 + (idx & 15)];
  }
  if (tid < 16) mlds[TT * 16 + tid] = 0;

  const int er = tid >> 4;
  const int ec = (tid & 15) * 2;
  const int grow = row0 + er;
  const int guu = u0 + ec;

  float bs0[4], bs1[4];
#pragma unroll
  for (int gt = 0; gt < 4; ++gt) {
    bs0[gt] = bias[gt * UU + guu];
    bs1[gt] = bias[gt * UU + guu + 1];
  }

  float cv0 = init_cs[(size_t)grow * UU + guu];
  float cv1 = init_cs[(size_t)grow * UU + guu + 1];
  float hv0 = init_cs[(size_t)BB * UU + grow * UU + guu];
  float hv1 = init_cs[(size_t)BB * UU + grow * UU + guu + 1];

  const unsigned wswz = ((unsigned)(er & 7)) << 4;
  const unsigned hoff = (unsigned)er * 2048u + ((((unsigned)guu) * 2u) ^ wswz);

  { // publish h(0) (masked) into buf 0
    int m0 = masks[grow];                        // masks[0][grow]
    float s = m0 ? 0.f : 1.f;
    char* base = (char*)hglob + (size_t)g * 32768 + hoff;
    unsigned pv = ((unsigned)f2bf(hv1 * s) << 16) | f2bf(hv0 * s);
    *(unsigned*)base = pv;
  }
  __syncthreads();                               // full drain (prologue only)
  if (tid == 0) fl[sb] = 1;
  { // all-wave poll
    unsigned v;
    do { v = __hip_atomic_load(&fl[lane & 31], __ATOMIC_RELAXED, __HIP_MEMORY_SCOPE_AGENT); }
    while (!__all(v >= 1));
  }

  // swizzled A-frag base pointers (XOR bank swizzle bits 4-6)
  const unsigned rswz = ((unsigned)(l15 & 7)) << 4;
  const char* hp0 = hlds_c + l15 * 2048 + (((unsigned)(kg * 16 + 0)) ^ rswz);
  const char* hp1 = hlds_c + l15 * 2048 + (((unsigned)(kg * 16 + 64)) ^ rswz);

  // staging address: row = tid>>5 (j=0) / 8+(tid>>5) (j=1), 16B chunk tid&31
  const unsigned sbase = ((unsigned)(tid >> 5)) * 2048u + ((unsigned)(tid & 31)) * 16u;

  // xz(0) prefetch (plain loads; compiler-managed wait)
  unsigned xz_cur[4], xz_nxt[4];
  {
    const size_t xr0 = ((size_t)grow) * NZ + guu;
#pragma unroll
    for (int gt = 0; gt < 4; ++gt)
      xz_cur[gt] = *(const unsigned*)(xz + xr0 + gt * UU);
  }

  for (int t = 0; t < TT; ++t) {
    const char* gsrc = (const char*)hglob + ((size_t)((t & 1) * 8 + g)) * 32768;

    // --- issue all 8 stage loads (oldest in FIFO), quarter order
    u32x4 sv[8];
#pragma unroll
    for (int q = 0; q < 4; ++q) {
#pragma unroll
      for (int j = 0; j < 2; ++j) {
        const char* ap = gsrc + sbase + j * 16384 + q * 512;
        asm volatile("global_load_dwordx4 %0, %1, off sc0" : "=v"(sv[q * 2 + j]) : "v"(ap));
      }
    }
    // --- issue xz(t+1) prefetch (newest; retired by this step's publish wait)
    {
      const int t1 = (t + 1 < TT) ? t + 1 : t;
      const char* xb = (const char*)xz + (((size_t)(t1 * BB + grow)) * NZ + guu) * 2;
#pragma unroll
      for (int gt = 0; gt < 4; ++gt) {
        const void* ap = xb + gt * (UU * 2);
        asm volatile("global_load_dword %0, %1, off" : "=v"(xz_nxt[gt]) : "v"(ap));
      }
    }

    f32x4 acc0 = {0.f, 0.f, 0.f, 0.f};
    f32x4 acc1 = {0.f, 0.f, 0.f, 0.f};

    SCAN_QUARTER(0, "vmcnt(9)")
    SCAN_QUARTER(1, "vmcnt(7)")
    SCAN_QUARTER(2, "vmcnt(5)")
    SCAN_QUARTER(3, "vmcnt(3)")   // all stage retired; xz(t+1) stays in flight

    // --- exchange gates across waves via LDS (lgkm-only barrier: NO vmcnt drain)
#pragma unroll
    for (int j = 0; j < 4; ++j) {
      zlds[wave][kg * 4 + j][l15] = acc0[j];
      zlds[wave][kg * 4 + j][16 + l15] = acc1[j];
    }
    asm volatile("s_waitcnt lgkmcnt(0)" ::: "memory");
    __builtin_amdgcn_sched_barrier(0);
    __builtin_amdgcn_s_barrier();
    __builtin_amdgcn_sched_barrier(0);

    // --- gate math (xz_cur: retired by LAST step's publish vmcnt(1))
    const int mcur = mlds[t * 16 + er];
    const int mnxt = mlds[(t + 1) * 16 + er];
    float z0[4], z1[4];
#pragma unroll
    for (int gt = 0; gt < 4; ++gt) {
      z0[gt] = zlds[gt][er][ec]     + bs0[gt] + bf2f((unsigned short)(xz_cur[gt] & 0xffffu));
      z1[gt] = zlds[gt][er][ec + 1] + bs1[gt] + bf2f((unsigned short)(xz_cur[gt] >> 16));
    }
    const float sm = mcur ? 0.f : 1.f;
    cv0 *= sm; cv1 *= sm;
    {
      float ig = sigm(z0[0]), fg = sigm(z0[1]), og = sigm(z0[2]), ug = tanh_(z0[3]);
      cv0 = fg * cv0 + ig * ug;
      hv0 = og * tanh_(cv0);
    }
    {
      float ig = sigm(z1[0]), fg = sigm(z1[1]), og = sigm(z1[2]), ug = tanh_(z1[3]);
      cv1 = fg * cv1 + ig * ug;
      hv1 = og * tanh_(cv1);
    }

    // --- publish: h store (L2) then out store; vmcnt(1) = xz(t+1)+h retired
    {
      const float sn = mnxt ? 0.f : 1.f;
      char* hdst = (char*)hglob + ((size_t)(((t + 1) & 1) * 8 + g)) * 32768 + hoff;
      unsigned pv = ((unsigned)f2bf(hv1 * sn) << 16) | f2bf(hv0 * sn);
      asm volatile("global_store_dword %0, %1, off" :: "v"(hdst), "v"(pv) : "memory");
      float* odst = out + (size_t)t * (BB * UU) + (size_t)grow * UU + guu;
      f32x2 ov = {hv0, hv1};
      asm volatile("global_store_dwordx2 %0, %1, off" :: "v"(odst), "v"(ov) : "memory");
    }
    asm volatile("s_waitcnt vmcnt(1)" ::: "memory");
    __builtin_amdgcn_sched_barrier(0);
    __builtin_amdgcn_s_barrier();                // all waves' h stores acked
    if (tid == 0) fl[sb] = (unsigned)(t + 2);    // publish step count
    { // all-wave poll; no release barrier (each wave verifies global cond)
      const unsigned tgt = (unsigned)(t + 2);
      unsigned v;
      do { v = __hip_atomic_load(&fl[lane & 31], __ATOMIC_RELAXED, __HIP_MEMORY_SCOPE_AGENT); }
      while (!__all(v >= tgt));
    }

#pragma unroll
    for (int gt = 0; gt < 4; ++gt) xz_cur[gt] = xz_nxt[gt];
  }

  // final states: [c ; h] appended after out
  float* so = out + (size_t)TT * BB * UU;
  *(f32x2*)(so + (size_t)grow * UU + guu) = (f32x2){cv0, cv1};
  *(f32x2*)(so + (size_t)BB * UU + grow * UU + guu) = (f32x2){hv0, hv1};
}

// ---------------------------------------------------------------------------
extern "C" void kernel_launch(void* const* d_in, const int* in_sizes, int n_in,
                              void* d_out, int out_size, void* d_ws, size_t ws_size,
                              hipStream_t stream) {
  const float* inputs  = (const float*)d_in[0];  // [256][128][1024]
  const float* states  = (const float*)d_in[1];  // [2][128][1024]
  const int*   masks   = (const int*)d_in[2];    // [256][128]
  const float* kernelx = (const float*)d_in[3];  // [1024][4096]
  const float* kernelh = (const float*)d_in[4];  // [1024][4096]
  const float* bias    = (const float*)d_in[5];  // [4096]
  float* out = (float*)d_out;
  char* ws = (char*)d_ws;

  unsigned* flags       = (unsigned*)ws;                                 // 2KB
  unsigned short* hglob = (unsigned short*)(ws + 65536);                 // 512KB
  unsigned short* WhT   = (unsigned short*)(ws + (size_t)2  * 1048576);  // 8MB
  unsigned short* WxT   = (unsigned short*)(ws + (size_t)10 * 1048576);  // 8MB
  unsigned short* Abf   = (unsigned short*)(ws + (size_t)18 * 1048576);  // 64MB
  unsigned short* xzbig = (unsigned short*)(ws + (size_t)82 * 1048576);  // 256MB

  k_transpose<<<dim3(64, 16), dim3(256), 0, stream>>>(kernelx, WxT);
  k_transpose<<<dim3(64, 16), dim3(256), 0, stream>>>(kernelh, WhT);
  k_convert<<<dim3(16384), dim3(256), 0, stream>>>(inputs, Abf, (TT * BB * DD) / 8);
  k_gemm_bf<<<dim3(8192), dim3(256), 0, stream>>>(Abf, WxT, xzbig);
  hipMemsetAsync(flags, 0, 2048, stream);
  k_scan<<<dim3(256), dim3(256), 0, stream>>>(states, masks, WhT, bias, xzbig,
                                              out, hglob, flags);
}